// Round 8
// baseline (119.132 us; speedup 1.0000x reference)
//
#include <hip/hip_runtime.h>
#include <stdint.h>

// Match XLA fp32 semantics: mul and add are separate HLO ops, never contracted
// into FMA. hipcc default is -ffp-contract=fast-honor-pragmas, so this pragma
// is honored; critical chains additionally use __fmul_rn/__fadd_rn.
#pragma clang fp contract(off)

#define NPIX (16 * 256 * 256)  // 1048576 pixels
#define NCAT 8
// Posterior-matrix LDS row stride in words. 260 % 32 == 4 -> for a fixed X,
// the 8 possible x_t rows map to 8 disjoint 4-bank quads => ds_read_b128 is
// bank-conflict-free across lanes with mixed x_t. 260*4 = 1040 B, 16B-aligned.
#define MSTRIDE 260

__device__ __forceinline__ uint32_t rotl32(uint32_t x, int r) {
  return (x << r) | (x >> (32 - r));
}

// threefry2x32 with key (0, 42) [jax.random.key(42)], counter (0, idx),
// returning x0 ^ x1 — the JAX "threefry_partitionable" 32-bit draw.
// Verified bit-exact vs reference in round 2 (zero argmax flips).
__device__ __forceinline__ uint32_t tf_bits(uint32_t idx) {
  const uint32_t ks0 = 0u;
  const uint32_t ks1 = 42u;
  const uint32_t ks2 = 0x1BD11BDAu ^ ks0 ^ ks1;
  uint32_t x0 = 0u + ks0;   // counts_hi = 0  (size < 2^32)
  uint32_t x1 = idx + ks1;  // counts_lo = flat index
#define TF4(ra, rb, rc, rd)                  \
  x0 += x1; x1 = rotl32(x1, ra); x1 ^= x0;   \
  x0 += x1; x1 = rotl32(x1, rb); x1 ^= x0;   \
  x0 += x1; x1 = rotl32(x1, rc); x1 ^= x0;   \
  x0 += x1; x1 = rotl32(x1, rd); x1 ^= x0;
  TF4(13, 15, 26, 6)  x0 += ks1; x1 += ks2 + 1u;
  TF4(17, 29, 16, 24) x0 += ks2; x1 += ks0 + 2u;
  TF4(13, 15, 26, 6)  x0 += ks0; x1 += ks1 + 3u;
  TF4(17, 29, 16, 24) x0 += ks1; x1 += ks2 + 4u;
  TF4(13, 15, 26, 6)  x0 += ks2; x1 += ks0 + 5u;
#undef TF4
  return x0 ^ x1;
}

// jax.random.gumbel element: -log(-log(uniform(tiny, 1))), fp32, bit-literal.
__device__ __forceinline__ float gumbel_at(uint32_t idx) {
  const float kTiny = 1.1754943508222875e-38f;  // finfo(f32).tiny
  uint32_t bits = tf_bits(idx);
  float f = __uint_as_float((bits >> 9) | 0x3f800000u) - 1.0f;
  f = __fadd_rn(__fmul_rn(f, 1.0f), kTiny);
  f = fmaxf(kTiny, f);
  return -logf(-logf(f));
}

// 2 pixels/thread: pixel pA = blk*512+tid and pB = pA+256. Two independent
// dataflows per stage give the scheduler parallel threefry/trans/div chains
// to interleave (round-2 VALUBusy was 64% — latency-bound, not issue-bound).
__global__ __launch_bounds__(256) void catdiff_sample_kernel(
    const int* __restrict__ x_t, const float* __restrict__ pred,
    const int* __restrict__ t, const float* __restrict__ Qs,
    const float* __restrict__ Qbs, float* __restrict__ out_idx,
    float* __restrict__ out_probs) {
  __shared__ float sL[64];           // Qs[t[b]]      row-major [row][col]
  __shared__ float sR[64];           // Qbs[t[b]-1]   [X][c]
  __shared__ float sDen[64];         // denom[xt][X]
  __shared__ float sM[8 * MSTRIDE];  // normalized posterior M[xt][X][c], padded

  const int tid = threadIdx.x;
  const int pA = blockIdx.x * 512 + tid;  // 512 pixels per block
  const int pB = pA + 256;
  const int b = blockIdx.x >> 7;  // 128 blocks per batch image (block-uniform)

  // Issue global loads first so HBM latency hides under the precompute phase.
  const float4 prA0 = *reinterpret_cast<const float4*>(pred + (size_t)pA * 8);
  const float4 prA1 = *reinterpret_cast<const float4*>(pred + (size_t)pA * 8 + 4);
  const float4 prB0 = *reinterpret_cast<const float4*>(pred + (size_t)pB * 8);
  const float4 prB1 = *reinterpret_cast<const float4*>(pred + (size_t)pB * 8 + 4);
  const int xtA = x_t[pA];  // 0..7
  const int xtB = x_t[pB];
  const int tb = t[b];      // 1..999 (block-uniform)

  // ---- Per-block posterior precompute (bit-identical op order to reference:
  //      denom[X] = sum_c fmul(left[c], R[X,c]) ascending; M = fmul(..)/denom).
  if (tid < 64) {
    sL[tid] = Qs[tb * 64 + tid];
  } else if (tid < 128) {
    sR[tid - 64] = Qbs[(tb - 1) * 64 + (tid - 64)];
  }
  __syncthreads();

  if (tid < 64) {
    const int x = tid >> 3;  // hypothetical x_t value
    const int X = tid & 7;   // posterior row
    float d = 0.0f;
#pragma unroll
    for (int c = 0; c < NCAT; ++c)
      d = __fadd_rn(d, __fmul_rn(sL[c * 8 + x], sR[X * 8 + c]));
    sDen[tid] = d;
  }
  __syncthreads();

  {
    // 512 entries over 256 threads, 2 each: e = (xt<<6)|(X<<3)|c
#pragma unroll
    for (int k = 0; k < 2; ++k) {
      const int e = tid * 2 + k;
      const int x = e >> 6, X = (e >> 3) & 7, c = e & 7;
      sM[x * MSTRIDE + X * 8 + c] =
          __fmul_rn(sL[c * 8 + x], sR[X * 8 + c]) / sDen[(x << 3) | X];
    }
  }
  __syncthreads();

  // ---- x_probs = softmax(pred) for both pixels, stages interleaved for ILP
  float lg[2][NCAT] = {
      {prA0.x, prA0.y, prA0.z, prA0.w, prA1.x, prA1.y, prA1.z, prA1.w},
      {prB0.x, prB0.y, prB0.z, prB0.w, prB1.x, prB1.y, prB1.z, prB1.w}};
  float mx[2], e[2][NCAT], s[2], xp[2][NCAT];
#pragma unroll
  for (int q = 0; q < 2; ++q) {
    mx[q] = lg[q][0];
#pragma unroll
    for (int c = 1; c < NCAT; ++c) mx[q] = fmaxf(mx[q], lg[q][c]);
  }
#pragma unroll
  for (int q = 0; q < 2; ++q)
#pragma unroll
    for (int c = 0; c < NCAT; ++c) e[q][c] = expf(lg[q][c] - mx[q]);
#pragma unroll
  for (int q = 0; q < 2; ++q) {
    s[q] = 0.0f;
#pragma unroll
    for (int c = 0; c < NCAT; ++c) s[q] = __fadd_rn(s[q], e[q][c]);
  }
#pragma unroll
  for (int q = 0; q < 2; ++q)
#pragma unroll
    for (int c = 0; c < NCAT; ++c) xp[q][c] = e[q][c] / s[q];

  // ---- anc[c] = sum_X M[xt][X][c] * xp[X] (ascending X, uncontracted)
  float anc[2][NCAT];
#pragma unroll
  for (int q = 0; q < 2; ++q)
#pragma unroll
    for (int c = 0; c < NCAT; ++c) anc[q][c] = 0.0f;
  const float* MrowA = &sM[xtA * MSTRIDE];
  const float* MrowB = &sM[xtB * MSTRIDE];
#pragma unroll
  for (int X = 0; X < NCAT; ++X) {
    const float4 a0 = *reinterpret_cast<const float4*>(MrowA + X * 8);
    const float4 a1 = *reinterpret_cast<const float4*>(MrowA + X * 8 + 4);
    const float4 b0 = *reinterpret_cast<const float4*>(MrowB + X * 8);
    const float4 b1 = *reinterpret_cast<const float4*>(MrowB + X * 8 + 4);
    anc[0][0] = __fadd_rn(anc[0][0], __fmul_rn(a0.x, xp[0][X]));
    anc[0][1] = __fadd_rn(anc[0][1], __fmul_rn(a0.y, xp[0][X]));
    anc[0][2] = __fadd_rn(anc[0][2], __fmul_rn(a0.z, xp[0][X]));
    anc[0][3] = __fadd_rn(anc[0][3], __fmul_rn(a0.w, xp[0][X]));
    anc[0][4] = __fadd_rn(anc[0][4], __fmul_rn(a1.x, xp[0][X]));
    anc[0][5] = __fadd_rn(anc[0][5], __fmul_rn(a1.y, xp[0][X]));
    anc[0][6] = __fadd_rn(anc[0][6], __fmul_rn(a1.z, xp[0][X]));
    anc[0][7] = __fadd_rn(anc[0][7], __fmul_rn(a1.w, xp[0][X]));
    anc[1][0] = __fadd_rn(anc[1][0], __fmul_rn(b0.x, xp[1][X]));
    anc[1][1] = __fadd_rn(anc[1][1], __fmul_rn(b0.y, xp[1][X]));
    anc[1][2] = __fadd_rn(anc[1][2], __fmul_rn(b0.z, xp[1][X]));
    anc[1][3] = __fadd_rn(anc[1][3], __fmul_rn(b0.w, xp[1][X]));
    anc[1][4] = __fadd_rn(anc[1][4], __fmul_rn(b1.x, xp[1][X]));
    anc[1][5] = __fadd_rn(anc[1][5], __fmul_rn(b1.y, xp[1][X]));
    anc[1][6] = __fadd_rn(anc[1][6], __fmul_rn(b1.z, xp[1][X]));
    anc[1][7] = __fadd_rn(anc[1][7], __fmul_rn(b1.w, xp[1][X]));
  }

  // ---- x_{t-1} = argmax_c log(anc[c]) + gumbel (first-max ties, like argmax)
  const uint32_t gbA = (uint32_t)pA * 8u;
  const uint32_t gbB = (uint32_t)pB * 8u;
  float bestv[2];
  int besti[2] = {0, 0};
  bestv[0] = __fadd_rn(logf(anc[0][0]), gumbel_at(gbA + 0u));
  bestv[1] = __fadd_rn(logf(anc[1][0]), gumbel_at(gbB + 0u));
#pragma unroll
  for (int c = 1; c < NCAT; ++c) {
    float vA = __fadd_rn(logf(anc[0][c]), gumbel_at(gbA + (uint32_t)c));
    float vB = __fadd_rn(logf(anc[1][c]), gumbel_at(gbB + (uint32_t)c));
    if (vA > bestv[0]) { bestv[0] = vA; besti[0] = c; }
    if (vB > bestv[1]) { bestv[1] = vB; besti[1] = c; }
  }

  // t >= 1 always (randint(1, T)), so out = x_{t-1} everywhere.
  out_idx[pA] = (float)besti[0];  // mixed tuple -> harness reads buffer as f32
  out_idx[pB] = (float)besti[1];
  *reinterpret_cast<float4*>(out_probs + (size_t)pA * 8) =
      make_float4(anc[0][0], anc[0][1], anc[0][2], anc[0][3]);
  *reinterpret_cast<float4*>(out_probs + (size_t)pA * 8 + 4) =
      make_float4(anc[0][4], anc[0][5], anc[0][6], anc[0][7]);
  *reinterpret_cast<float4*>(out_probs + (size_t)pB * 8) =
      make_float4(anc[1][0], anc[1][1], anc[1][2], anc[1][3]);
  *reinterpret_cast<float4*>(out_probs + (size_t)pB * 8 + 4) =
      make_float4(anc[1][4], anc[1][5], anc[1][6], anc[1][7]);
}

extern "C" void kernel_launch(void* const* d_in, const int* in_sizes, int n_in,
                              void* d_out, int out_size, void* d_ws,
                              size_t ws_size, hipStream_t stream) {
  (void)in_sizes; (void)n_in; (void)out_size; (void)d_ws; (void)ws_size;
  const int*   x_t  = (const int*)d_in[0];
  const float* pred = (const float*)d_in[1];
  const int*   t    = (const int*)d_in[2];
  const float* Qs   = (const float*)d_in[3];
  const float* Qbs  = (const float*)d_in[4];
  float* out0 = (float*)d_out;          // argmax indices as f32 (1048576)
  float* out1 = out0 + NPIX;            // ancestral_probs     (8388608)

  dim3 grid(NPIX / 512), block(256);    // 2 pixels per thread
  hipLaunchKernelGGL(catdiff_sample_kernel, grid, block, 0, stream,
                     x_t, pred, t, Qs, Qbs, out0, out1);
}